// Round 10
// baseline (111.080 us; speedup 1.0000x reference)
//
#include <hip/hip_runtime.h>
#include <math.h>

#define NO_CH   144      // 4*16 + 80
#define NC      80
#define REGMAX  16
#define A_TOT   8400     // 80*80 + 40*40 + 20*20
#define HW0     6400
#define HW1     1600
#define HW2     400

// 128-anchor tiles, per level: L0 50, L1 13 (last nvalid=64), L2 4 (last nvalid=16)
#define T0      50
#define T1      13
#define T2      4
#define NTILES  (T0 + T1 + T2)   // 67

typedef float f32x4 __attribute__((ext_vector_type(4)));

__device__ __forceinline__ float rcpf(float x) { return __builtin_amdgcn_rcpf(x); }
__device__ __forceinline__ float sigmoidf(float x) {
    return rcpf(1.0f + __expf(-x));
}

// ---------------------------------------------------------------------------
// 128-anchor tile version. Theory: R3..R9 plateau at ~84us (62% of HBM peak)
// because every wave read covers only 256B of a channel row before a 25.6KB
// stride jump (short DRAM bursts). With 128-anchor tiles each wave load
// instruction covers 512B contiguous (2 rows x 64 lanes x 16B), doubling
// burst length. MLP was ruled out in R8/R9 (pinned loads, no change).
//  phase 1 (DFL): wave = group; lane=(rq=l>>5, q=l&31); 2 iters x 4 loads;
//                 channels rq*4+r+8i; xor-32 butterfly completes the 16-sum.
//  phase 2: scores 2 rows/instr -> sigmoid -> tile[80][129] (41KB LDS).
//  epilogues: boxes 2KB contiguous; scores f32x4 column reads, nt stores.
// ---------------------------------------------------------------------------
__global__ __launch_bounds__(256, 3) void fused_kernel(
    const float* __restrict__ f0, const float* __restrict__ f1,
    const float* __restrict__ f2, float* __restrict__ out_boxes,
    float* __restrict__ out_scores)
{
    __shared__ float tile[NC][129];     // 41.3 KB
    __shared__ float dist_lds[4][128];  // 2 KB

    const int b    = blockIdx.y;
    const int t    = blockIdx.x;
    const int tid  = threadIdx.x;
    const int lane = tid & 63;
    const int wv   = tid >> 6;

    const float* base; int hw, local, w, nvalid; float st; int a0;
    if (t < T0) {
        base = f0 + (size_t)b * NO_CH * HW0; hw = HW0; local = t * 128;
        w = 80; st = 8.0f;  nvalid = 128;               a0 = local;
    } else if (t < T0 + T1) {
        base = f1 + (size_t)b * NO_CH * HW1; hw = HW1; local = (t - T0) * 128;
        w = 40; st = 16.0f; nvalid = min(128, HW1 - local); a0 = HW0 + local;
    } else {
        base = f2 + (size_t)b * NO_CH * HW2; hw = HW2; local = (t - T0 - T1) * 128;
        w = 20; st = 32.0f; nvalid = min(128, HW2 - local); a0 = HW0 + HW1 + local;
    }

    // ---- phase 1: DFL. wave = group g; lane = (rq = lane>>5, q = lane&31) ----
    {
        const int g  = wv;
        const int rq = lane >> 5;        // 0/1: channel-quad pair selector
        const int q  = lane & 31;        // anchor quad (4 anchors)
        const bool act = (q * 4 < nvalid);

        float4 se = make_float4(0.f, 0.f, 0.f, 0.f);
        float4 sw = make_float4(0.f, 0.f, 0.f, 0.f);

        #pragma unroll
        for (int i = 0; i < 2; ++i) {
            #pragma unroll
            for (int r = 0; r < 4; ++r) {
                const int ch = rq * 4 + r + 8 * i;       // 0..15 within group
                float4 v = make_float4(0.f, 0.f, 0.f, 0.f);
                if (act)
                    v = *reinterpret_cast<const float4*>(
                        base + (size_t)(g * REGMAX + ch) * hw + local + q * 4);
                const float wgt = (float)ch;
                const float ex = __expf(v.x);
                const float ey = __expf(v.y);
                const float ez = __expf(v.z);
                const float ew = __expf(v.w);
                se.x += ex; se.y += ey; se.z += ez; se.w += ew;
                sw.x += ex * wgt; sw.y += ey * wgt; sw.z += ez * wgt; sw.w += ew * wgt;
            }
        }
        // xor-32: combine the two channel-quad halves (full 16-channel sums)
        se.x += __shfl_xor(se.x, 32, 64);
        se.y += __shfl_xor(se.y, 32, 64);
        se.z += __shfl_xor(se.z, 32, 64);
        se.w += __shfl_xor(se.w, 32, 64);
        sw.x += __shfl_xor(sw.x, 32, 64);
        sw.y += __shfl_xor(sw.y, 32, 64);
        sw.z += __shfl_xor(sw.z, 32, 64);
        sw.w += __shfl_xor(sw.w, 32, 64);

        if (rq == 0 && act) {
            const float4 dist = make_float4(sw.x * rcpf(se.x), sw.y * rcpf(se.y),
                                            sw.z * rcpf(se.z), sw.w * rcpf(se.w));
            *reinterpret_cast<float4*>(&dist_lds[g][q * 4]) = dist;
        }
    }

    // ---- phase 2: scores. 2 rows per wave instr; 10 iters; sigmoid -> tile ----
    {
        const float* ssc = base + (size_t)(4 * REGMAX) * hw + local;
        const int q    = lane & 31;        // anchor quad
        const int rsub = lane >> 5;        // row parity within pair
        const bool act = (q * 4 < nvalid);
        #pragma unroll
        for (int i = 0; i < 10; ++i) {
            const int r = wv * 20 + rsub + 2 * i;
            float4 u = make_float4(0.f, 0.f, 0.f, 0.f);
            if (act)
                u = *reinterpret_cast<const float4*>(ssc + (size_t)r * hw + q * 4);
            tile[r][q * 4 + 0] = sigmoidf(u.x);
            tile[r][q * 4 + 1] = sigmoidf(u.y);
            tile[r][q * 4 + 2] = sigmoidf(u.z);
            tile[r][q * 4 + 3] = sigmoidf(u.w);
        }
    }

    __syncthreads();

    // ---- boxes out: 4*nvalid contiguous floats (<=512), 2 per thread ----
    #pragma unroll
    for (int p = 0; p < 2; ++p) {
        const int idx = tid + 256 * p;
        if (idx < 4 * nvalid) {
            const int la   = idx >> 2;
            const int comp = idx & 3;
            const int gl   = local + la;
            int iy, ix;
            if (w == 80)      { iy = gl / 80; ix = gl - iy * 80; }
            else if (w == 40) { iy = gl / 40; ix = gl - iy * 40; }
            else              { iy = gl / 20; ix = gl - iy * 20; }
            const float axy = ((comp & 1) ? (float)iy : (float)ix) + 0.5f;
            const float d   = dist_lds[comp][la];
            const float val = (axy + ((comp >= 2) ? d : -d)) * st;
            __builtin_nontemporal_store(
                val, out_boxes + ((size_t)b * A_TOT + a0) * 4 + idx);
        }
    }

    // ---- scores out: f32x4 stores, column reads from the tile ----
    float* dst = out_scores + ((size_t)b * A_TOT + a0) * NC;
    const int nq = nvalid * (NC / 4);          // up to 2560
    for (int j4 = tid; j4 < nq; j4 += 256) {
        const int la = j4 / 20;
        const int c0 = (j4 - la * 20) * 4;
        f32x4 o;
        o.x = tile[c0 + 0][la];
        o.y = tile[c0 + 1][la];
        o.z = tile[c0 + 2][la];
        o.w = tile[c0 + 3][la];
        __builtin_nontemporal_store(o, reinterpret_cast<f32x4*>(dst) + j4);
    }
}

extern "C" void kernel_launch(void* const* d_in, const int* in_sizes, int n_in,
                              void* d_out, int out_size, void* d_ws, size_t ws_size,
                              hipStream_t stream) {
    const float* f0 = (const float*)d_in[0];
    const float* f1 = (const float*)d_in[1];
    const float* f2 = (const float*)d_in[2];

    const int b = in_sizes[0] / (NO_CH * HW0);   // 64

    float* out_boxes  = (float*)d_out;
    float* out_scores = out_boxes + (size_t)b * A_TOT * 4;

    dim3 grid(NTILES, b);
    fused_kernel<<<grid, dim3(256), 0, stream>>>(f0, f1, f2, out_boxes, out_scores);
}

// Round 11
// 85.231 us; speedup vs baseline: 1.3033x; 1.3033x over previous
//
#include <hip/hip_runtime.h>
#include <math.h>

#define NO_CH   144      // 4*16 + 80
#define NC      80
#define REGMAX  16
#define A_TOT   8400     // 80*80 + 40*40 + 20*20
#define HW0     6400
#define HW1     1600
#define HW2     400
#define SC_BLOCKS 132    // 64-anchor tiles; levels are 64-aligned

typedef float f32x4 __attribute__((ext_vector_type(4)));

__device__ __forceinline__ float rcpf(float x) { return __builtin_amdgcn_rcpf(x); }
__device__ __forceinline__ float sigmoidf(float x) {
    return rcpf(1.0f + __expf(-x));
}

// ---------------------------------------------------------------------------
// FINAL (= R7, best measured 84.0us = 93% of the 6.29 TB/s copy ceiling on
// 491 MB app bytes).
//  one block = 64 anchors of one batch; boxes (DFL) + scores.
//  phase 1: wave=group butterfly DFL -> dist_lds (1KB)
//  phase 2: scores float4 loads -> sigmoid -> LDS tile [80][65]
//  single barrier; boxes 1KB contiguous; scores f32x4 column-read nt stores.
//  Tested and rejected: block-range fusion (R2, occupancy), zero-LDS direct
//  stores (R6, write amplification 1.5x / 5x slower), load hoisting + sched
//  fence (R8/R9, neutral - TLP already covers latency), 128-anchor tiles
//  (R10, occupancy loss > burst gain).
// ---------------------------------------------------------------------------
__global__ __launch_bounds__(256, 6) void fused_kernel(
    const float* __restrict__ f0, const float* __restrict__ f1,
    const float* __restrict__ f2, float* __restrict__ out_boxes,
    float* __restrict__ out_scores)
{
    __shared__ float tile[NC][65];     // 20.8 KB
    __shared__ float dist_lds[4][64];  // 1 KB

    const int b   = blockIdx.y;
    const int a0  = blockIdx.x * 64;
    const int tid = threadIdx.x;

    const float* base; int hw, local; float st;
    if (a0 < HW0) {
        base = f0 + (size_t)b * NO_CH * HW0; hw = HW0; local = a0; st = 8.0f;
    } else if (a0 < HW0 + HW1) {
        base = f1 + (size_t)b * NO_CH * HW1; hw = HW1; local = a0 - HW0; st = 16.0f;
    } else {
        base = f2 + (size_t)b * NO_CH * HW2; hw = HW2; local = a0 - HW0 - HW1; st = 32.0f;
    }

    const int nvalid = min(64, A_TOT - a0);

    // ---- phase 1: DFL expectation (wave = group, butterfly over channels) ----
    {
        const int g    = tid >> 6;       // wave = group
        const int lane = tid & 63;
        const int laq  = lane & 15;      // anchor quad (4 anchors)
        const int rq   = lane >> 4;      // channel quad within group (0..3)

        float4 se = make_float4(0.f, 0.f, 0.f, 0.f);
        float4 sw = make_float4(0.f, 0.f, 0.f, 0.f);

        if (laq * 4 < nvalid) {
            const float* s = base + (size_t)(g * REGMAX + rq * 4) * hw + local + laq * 4;
            #pragma unroll
            for (int r = 0; r < 4; ++r) {
                const float4 v = *reinterpret_cast<const float4*>(s + (size_t)r * hw);
                const float wgt = (float)(rq * 4 + r);
                const float ex = __expf(v.x);
                const float ey = __expf(v.y);
                const float ez = __expf(v.z);
                const float ew = __expf(v.w);
                se.x += ex; se.y += ey; se.z += ez; se.w += ew;
                sw.x += ex * wgt; sw.y += ey * wgt; sw.z += ez * wgt; sw.w += ew * wgt;
            }
        }
        #pragma unroll
        for (int m = 16; m <= 32; m <<= 1) {
            se.x += __shfl_xor(se.x, m, 64);
            se.y += __shfl_xor(se.y, m, 64);
            se.z += __shfl_xor(se.z, m, 64);
            se.w += __shfl_xor(se.w, m, 64);
            sw.x += __shfl_xor(sw.x, m, 64);
            sw.y += __shfl_xor(sw.y, m, 64);
            sw.z += __shfl_xor(sw.z, m, 64);
            sw.w += __shfl_xor(sw.w, m, 64);
        }
        if (rq == 0 && laq * 4 < nvalid) {
            const float4 dist = make_float4(sw.x * rcpf(se.x), sw.y * rcpf(se.y),
                                            sw.z * rcpf(se.z), sw.w * rcpf(se.w));
            *reinterpret_cast<float4*>(&dist_lds[g][laq * 4]) = dist;
        }
    }

    // ---- phase 2: scores sigmoid into LDS tile ----
    const float* ssc = base + (size_t)(4 * REGMAX) * hw + local;
    if (nvalid == 64) {
        const int quad = tid & 15;
        const int r0   = tid >> 4;
        #pragma unroll
        for (int i = 0; i < 5; ++i) {
            const int r = r0 + 16 * i;
            const float4 v = *reinterpret_cast<const float4*>(
                ssc + (size_t)r * hw + quad * 4);
            tile[r][quad * 4 + 0] = sigmoidf(v.x);
            tile[r][quad * 4 + 1] = sigmoidf(v.y);
            tile[r][quad * 4 + 2] = sigmoidf(v.z);
            tile[r][quad * 4 + 3] = sigmoidf(v.w);
        }
    } else {
        const int col = tid & 63;
        const int r0  = tid >> 6;
        if (col < nvalid) {
            #pragma unroll
            for (int i = 0; i < 20; ++i) {
                const int r = r0 + 4 * i;
                tile[r][col] = sigmoidf(ssc[(size_t)r * hw + col]);
            }
        }
    }

    __syncthreads();

    // ---- boxes out: 4*nvalid contiguous floats, one per thread ----
    if (tid < 4 * nvalid) {
        const int la   = tid >> 2;
        const int comp = tid & 3;
        const int gl   = local + la;
        int ix, iy;
        if (hw == HW0)      { iy = gl / 80; ix = gl - iy * 80; }
        else if (hw == HW1) { iy = gl / 40; ix = gl - iy * 40; }
        else                { iy = gl / 20; ix = gl - iy * 20; }
        const float axy = ((comp & 1) ? (float)iy : (float)ix) + 0.5f;
        const float d   = dist_lds[comp][la];
        const float val = (axy + ((comp >= 2) ? d : -d)) * st;
        __builtin_nontemporal_store(
            val, out_boxes + ((size_t)b * A_TOT + a0) * 4 + tid);
    }

    // ---- scores out: f32x4 stores, column reads from the tile ----
    // j4 indexes output quads: la = j4/20, c0 = 4*(j4%20); 80%4==0 so a quad
    // never straddles an anchor row. Stores are 16B/lane, wave-contiguous.
    float* dst = out_scores + ((size_t)b * A_TOT + a0) * NC;
    const int nq = nvalid * (NC / 4);          // 1280 (or 320 on tail tile)
    for (int j4 = tid; j4 < nq; j4 += 256) {
        const int la = j4 / 20;
        const int c0 = (j4 - la * 20) * 4;
        f32x4 o;
        o.x = tile[c0 + 0][la];
        o.y = tile[c0 + 1][la];
        o.z = tile[c0 + 2][la];
        o.w = tile[c0 + 3][la];
        __builtin_nontemporal_store(o, reinterpret_cast<f32x4*>(dst) + j4);
    }
}

extern "C" void kernel_launch(void* const* d_in, const int* in_sizes, int n_in,
                              void* d_out, int out_size, void* d_ws, size_t ws_size,
                              hipStream_t stream) {
    const float* f0 = (const float*)d_in[0];
    const float* f1 = (const float*)d_in[1];
    const float* f2 = (const float*)d_in[2];

    const int b = in_sizes[0] / (NO_CH * HW0);   // 64

    float* out_boxes  = (float*)d_out;
    float* out_scores = out_boxes + (size_t)b * A_TOT * 4;

    dim3 grid(SC_BLOCKS, b);
    fused_kernel<<<grid, dim3(256), 0, stream>>>(f0, f1, f2, out_boxes, out_scores);
}